// Round 9
// baseline (124.899 us; speedup 1.0000x reference)
//
#include <hip/hip_runtime.h>
#include <hip/hip_bf16.h>
#include <math.h>

#define Bz 4
#define Nn 512
#define Hh 512
#define NHh 8
#define HDd 64
#define DEe 64
#define DFFf 2048
#define EPSs 1e-5f
#define QS 1536      // fused QKV row stride
#define GS 3072      // fused gate row stride

typedef __attribute__((ext_vector_type(8))) short bf16x8;
typedef __attribute__((ext_vector_type(4))) short bf16x4;
typedef __attribute__((ext_vector_type(4))) float f32x4;

__device__ inline short f2bf(float x) {
    unsigned u = __builtin_bit_cast(unsigned, x);
    unsigned r = (u + 0x7FFFu + ((u >> 16) & 1u)) >> 16;
    return (short)r;
}
__device__ inline float b2f(unsigned short u) {
    unsigned v = ((unsigned)u) << 16;
    return __builtin_bit_cast(float, v);
}
__device__ inline void gld16(const void* g, void* l) {
    __builtin_amdgcn_global_load_lds(
        (const __attribute__((address_space(1))) void*)g,
        (__attribute__((address_space(3))) void*)l, 16, 0, 0);
}

// ---------------------------------------------------------------------------
// prep: f32->bf16 copies (opt. pitched) | embb=emb/512 pad256 | bias folds |
// Wo transpose | per-row histq (dist rows) | per-col histk (dist cols).
// ---------------------------------------------------------------------------
struct CvtSeg { const float* src; unsigned short* dst; int n, ncols, pitch; };
struct PrepArgs {
    CvtSeg cs[12];
    const float* emb; unsigned short* embb;
    const float* dist;
    unsigned short* AQ; unsigned short* AK;   // [2048,768], hist -> col 512
    const float* Wo; unsigned short* woT;
    const float* fW[3]; const float* fv[3]; const float* fb[3]; float* fo[3];
};

__global__ __launch_bounds__(256) void prep_kernel(PrepArgs a)
{
    __shared__ char lds[17408];
    int t = threadIdx.x;
    int blk = blockIdx.x;
    if (blk < 512) {
        for (int sg = 0; sg < 12; ++sg) {
            CvtSeg c = a.cs[sg];
            int n4 = c.n >> 2;
            for (int i = blk * 256 + t; i < n4; i += 512 * 256) {
                int base = i * 4;
                int row = base / c.ncols;
                int col = base - row * c.ncols;
                float4 v = *(const float4*)(c.src + base);
                ushort4 o = {(unsigned short)f2bf(v.x), (unsigned short)f2bf(v.y),
                             (unsigned short)f2bf(v.z), (unsigned short)f2bf(v.w)};
                *(ushort4*)(c.dst + (size_t)row * c.pitch + col) = o;
            }
        }
        const float sc = 1.0f / 512.0f;
        for (int i = blk * 256 + t; i < 4096; i += 512 * 256) {
            ushort4 o = {0, 0, 0, 0};
            if (i * 4 < 201 * 64) {
                float4 v = *(const float4*)(a.emb + i * 4);
                o.x = (unsigned short)f2bf(v.x * sc);
                o.y = (unsigned short)f2bf(v.y * sc);
                o.z = (unsigned short)f2bf(v.z * sc);
                o.w = (unsigned short)f2bf(v.w * sc);
            }
            *(ushort4*)(a.embb + i * 4) = o;
        }
    } else if (blk < 552) {
        // bias folds: out = base + W @ vec   (all K=512)
        int fid = blk - 512;
        int f, ob;
        if (fid < 8)       { f = 0; ob = fid * 64; }
        else if (fid < 16) { f = 1; ob = (fid - 8) * 64; }
        else               { f = 2; ob = (fid - 16) * 64; }
        int i = ob + (t >> 2), part = t & 3;
        const float* Wr = a.fW[f] + (size_t)i * 512 + part * 128;
        const float* vv = a.fv[f] + part * 128;
        float s = 0.f;
        for (int k = 0; k < 128; k += 4) {
            float4 w4 = *(const float4*)(Wr + k);
            float4 b4 = *(const float4*)(vv + k);
            s += w4.x * b4.x + w4.y * b4.y + w4.z * b4.z + w4.w * b4.w;
        }
        s += __shfl_xor(s, 1);
        s += __shfl_xor(s, 2);
        if (part == 0) a.fo[f][i] = a.fb[f][i] + s;
    } else if (blk < 616) {
        // woT[m][i] = Wo[i][m], bf16 out
        int tid = blk - 552;
        int ti = tid >> 3, tj = tid & 7;
        float (*T)[68] = (float (*)[68])lds;
        int rr = t >> 4, c4 = (t & 15) * 4;
#pragma unroll
        for (int p = 0; p < 4; ++p) {
            int r = rr + p * 16;
            float4 v = *(const float4*)(a.Wo + (size_t)(ti * 64 + r) * 512 + tj * 64 + c4);
            *(float4*)&T[r][c4] = v;
        }
        __syncthreads();
#pragma unroll
        for (int p = 0; p < 4; ++p) {
            int jr = rr + p * 16;
            ushort4 o = {(unsigned short)f2bf(T[c4 + 0][jr]),
                         (unsigned short)f2bf(T[c4 + 1][jr]),
                         (unsigned short)f2bf(T[c4 + 2][jr]),
                         (unsigned short)f2bf(T[c4 + 3][jr])};
            *(ushort4*)(a.woT + (size_t)(tj * 64 + jr) * 512 + ti * 64 + c4) = o;
        }
    } else if (blk < 2664) {
        // histq: one block per dist row
        int r = blk - 616;
        int* hist = (int*)lds;
        hist[t] = 0;
        __syncthreads();
        float2 v = *(const float2*)(a.dist + (size_t)r * 512 + t * 2);
        atomicAdd(&hist[min(max((int)v.x, 0), 200)], 1);
        atomicAdd(&hist[min(max((int)v.y, 0), 200)], 1);
        __syncthreads();
        a.AQ[(size_t)r * 768 + 512 + t] = (unsigned short)f2bf((float)hist[t]);
    } else {
        // histk: per-column histograms, 16 cols per block
        int idx = blk - 2664;
        int b = idx >> 5, jt = idx & 31;
        int j0 = jt * 16;
        int* h2 = (int*)lds;           // [16][256]
        for (int k = t; k < 4096; k += 256) h2[k] = 0;
        __syncthreads();
        int ri = t >> 4, jj = t & 15;
        for (int i0 = 0; i0 < 512; i0 += 16) {
            float v = a.dist[(size_t)(b * 512 + i0 + ri) * 512 + j0 + jj];
            atomicAdd(&h2[jj * 256 + min(max((int)v, 0), 200)], 1);
        }
        __syncthreads();
        for (int k = t; k < 4096; k += 256) {
            int jj2 = k >> 8, bin = k & 255;
            a.AK[(size_t)(b * 512 + j0 + jj2) * 768 + 512 + bin] =
                (unsigned short)f2bf((float)h2[k]);
        }
    }
}

// ---------------------------------------------------------------------------
// Grouped bf16 MFMA GEMM: per-segment {A,lda,Ks,W,ldw,bias,res,C,ldc}.
// LDS double-buffered 2-phase; inner loop identical to verified mgf.
// ---------------------------------------------------------------------------
struct Seg {
    const unsigned short* A; const unsigned short* W;
    const float* bias; const void* res; void* C;
    int lda, Ks, ldw, rlda, ldc, pad;
};
struct SegArgs { Seg s[6]; };

template<int BM, int BN, int RELU, int RESM, int OUTF, int HASB>
__global__ __launch_bounds__(256) void mgf_kernel(SegArgs sa, int SW)
{
    constexpr int WM = BM / 2, WN = BN / 2;
    constexpr int MT = WM / 16, NT = WN / 16;
    constexpr int IPA = BM / 32, IPB = BN / 32;
    __shared__ unsigned short As[2][BM * 64];
    __shared__ unsigned short Bs[2][BN * 64];
    int t = threadIdx.x, lane = t & 63, wid = t >> 6;
    int wm = wid >> 1, wn = wid & 1;
    int m0 = blockIdx.y * BM, n0 = blockIdx.x * BN;
    int seg = n0 / SW;
    const unsigned short* A = sa.s[seg].A;
    const unsigned short* W = sa.s[seg].W;
    int lda = sa.s[seg].lda, Ks = sa.s[seg].Ks, ldw = sa.s[seg].ldw;
    int nloc = n0 - seg * SW;
    int lrow8 = lane >> 3;
    int lunit = (lane & 7) ^ lrow8;

    f32x4 acc[MT][NT] = {};

    auto stage = [&](int buf, int kt) {
#pragma unroll
        for (int i = 0; i < IPA; ++i) {
            int c = wid * IPA + i;
            gld16(A + (size_t)(m0 + c * 8 + lrow8) * lda + kt + lunit * 8,
                  &As[buf][c * 512]);
        }
#pragma unroll
        for (int i = 0; i < IPB; ++i) {
            int c = wid * IPB + i;
            gld16(W + (size_t)(nloc + c * 8 + lrow8) * ldw + kt + lunit * 8,
                  &Bs[buf][c * 512]);
        }
    };

    stage(0, 0);
    __syncthreads();
    int cur = 0;
    for (int kt = 0; kt < Ks; kt += 64) {
        if (kt + 64 < Ks) stage(cur ^ 1, kt + 64);
#pragma unroll
        for (int kk = 0; kk < 2; ++kk) {
            bf16x8 fa[MT], fb[NT];
            int ub = kk * 4 + (lane >> 4);
#pragma unroll
            for (int mt = 0; mt < MT; ++mt) {
                int r = wm * WM + mt * 16 + (lane & 15);
                fa[mt] = *(const bf16x8*)&As[cur][r * 64 + ((ub ^ (r & 7)) << 3)];
            }
#pragma unroll
            for (int nt = 0; nt < NT; ++nt) {
                int r = wn * WN + nt * 16 + (lane & 15);
                fb[nt] = *(const bf16x8*)&Bs[cur][r * 64 + ((ub ^ (r & 7)) << 3)];
            }
#pragma unroll
            for (int mt = 0; mt < MT; ++mt)
#pragma unroll
                for (int nt = 0; nt < NT; ++nt)
                    acc[mt][nt] = __builtin_amdgcn_mfma_f32_16x16x32_bf16(
                        fa[mt], fb[nt], acc[mt][nt], 0, 0, 0);
        }
        __syncthreads();
        cur ^= 1;
    }

    int cr = (lane >> 4) * 4, ccl = lane & 15;
    const float* bias = sa.s[seg].bias;
    const void* res = sa.s[seg].res;
    int rlda = sa.s[seg].rlda, ldc = sa.s[seg].ldc;
    void* C = sa.s[seg].C;
#pragma unroll
    for (int mt = 0; mt < MT; ++mt) {
#pragma unroll
        for (int nt = 0; nt < NT; ++nt) {
            int lcol = nloc + wn * WN + nt * 16 + ccl;
            float bv = HASB ? bias[lcol] : 0.f;
#pragma unroll
            for (int r = 0; r < 4; ++r) {
                int row = m0 + wm * WM + mt * 16 + cr + r;
                float o = acc[mt][nt][r] + bv;
                if (RESM == 1)
                    o += ((const float*)res)[(size_t)row * rlda + lcol];
                if (RESM == 2)
                    o += b2f(((const unsigned short*)res)[(size_t)row * rlda + lcol]);
                if (RELU) o = fmaxf(o, 0.f);
                if (OUTF)
                    ((float*)C)[(size_t)row * ldc + lcol] = o;
                else
                    ((unsigned short*)C)[(size_t)row * ldc + lcol] =
                        (unsigned short)f2bf(o);
            }
        }
    }
}

// ---------------------------------------------------------------------------
// MFMA flash attention reading fused QKV [M, 1536] (Q +0, K +512, V +1024).
// ---------------------------------------------------------------------------
__global__ __launch_bounds__(256) void attn_mfma_kernel(
    const unsigned short* __restrict__ QKV, const float* __restrict__ mask,
    unsigned short* __restrict__ AO)
{
    __shared__ unsigned short Qs[64 * 64];
    __shared__ unsigned short Ks[64 * 64];
    __shared__ unsigned short Vt[64 * 64];
    __shared__ float Ms[64 * 65];
    __shared__ unsigned short Pl[4][16 * 72];

    int t = threadIdx.x;
    int lane = t & 63;
    int wq = t >> 6;
    int g = lane >> 4, cc = lane & 15;
    int q0 = blockIdx.x * 64;
    int h = blockIdx.y, b = blockIdx.z;

    int lr = t >> 2;
    int u0 = (t & 3) * 2;
    int c0f = (t & 3) * 16;

    {
        const unsigned short* src =
            QKV + ((size_t)(b * Nn + q0 + lr)) * QS + h * HDd + u0 * 8;
        bf16x8 p0 = *(const bf16x8*)(src);
        bf16x8 p1 = *(const bf16x8*)(src + 8);
        *(bf16x8*)&Qs[lr * 64 + ((u0 ^ (lr & 7)) << 3)] = p0;
        *(bf16x8*)&Qs[lr * 64 + (((u0 + 1) ^ (lr & 7)) << 3)] = p1;
    }

    const unsigned short* Krow =
        QKV + ((size_t)(b * Nn + lr)) * QS + 512 + h * HDd + u0 * 8;
    int vkey = t >> 4;
    int vd0 = (t & 15) * 4;
    const unsigned short* Vbase =
        QKV + ((size_t)(b * Nn)) * QS + 1024 + h * HDd + vd0;
    const float* Mrow = mask + ((size_t)(b * Nn + q0 + lr)) * Nn + c0f;

    bf16x8 kr0, kr1;
    ushort4 vr[4];
    float4 mreg[4];
    auto issue = [&](int kc) {
        int k0 = kc * 64;
        const unsigned short* kp = Krow + (size_t)k0 * QS;
        kr0 = *(const bf16x8*)(kp);
        kr1 = *(const bf16x8*)(kp + 8);
        const float* mp = Mrow + k0;
        mreg[0] = *(const float4*)(mp);
        mreg[1] = *(const float4*)(mp + 4);
        mreg[2] = *(const float4*)(mp + 8);
        mreg[3] = *(const float4*)(mp + 12);
#pragma unroll
        for (int p = 0; p < 4; ++p)
            vr[p] = *(const ushort4*)(Vbase + (size_t)(k0 + vkey + p * 16) * QS);
    };
    issue(0);
    __syncthreads();

    bf16x8 qf0 = *(bf16x8*)&Qs[(wq * 16 + cc) * 64 + (((0 * 4 + g) ^ (cc & 7)) << 3)];
    bf16x8 qf1 = *(bf16x8*)&Qs[(wq * 16 + cc) * 64 + (((1 * 4 + g) ^ (cc & 7)) << 3)];

    const float scale = 0.125f;
    float m_run = -1e30f, l_run = 0.f;
    f32x4 o[4] = {};

    for (int kc = 0; kc < 8; ++kc) {
        {
            *(bf16x8*)&Ks[lr * 64 + ((u0 ^ (lr & 7)) << 3)] = kr0;
            *(bf16x8*)&Ks[lr * 64 + (((u0 + 1) ^ (lr & 7)) << 3)] = kr1;

            float* msr = &Ms[lr * 65 + c0f];
            msr[0] = mreg[0].x;  msr[1] = mreg[0].y;  msr[2] = mreg[0].z;  msr[3] = mreg[0].w;
            msr[4] = mreg[1].x;  msr[5] = mreg[1].y;  msr[6] = mreg[1].z;  msr[7] = mreg[1].w;
            msr[8] = mreg[2].x;  msr[9] = mreg[2].y;  msr[10] = mreg[2].z; msr[11] = mreg[2].w;
            msr[12] = mreg[3].x; msr[13] = mreg[3].y; msr[14] = mreg[3].z; msr[15] = mreg[3].w;

#pragma unroll
            for (int p = 0; p < 4; ++p) {
                int key = vkey + p * 16;
                unsigned short vals[4] = {vr[p].x, vr[p].y, vr[p].z, vr[p].w};
#pragma unroll
                for (int jj = 0; jj < 4; ++jj) {
                    int j = (jj + (t >> 2)) & 3;
                    int d = vd0 + j;
                    Vt[d * 64 + (key ^ ((d & 7) << 3))] = vals[j];
                }
            }
        }
        __syncthreads();
        if (kc < 7) issue(kc + 1);

        f32x4 s[4] = {};
        __builtin_amdgcn_s_setprio(1);
#pragma unroll
        for (int kt = 0; kt < 4; ++kt) {
            int rA = kt * 16 + cc;
            bf16x8 a0 = *(bf16x8*)&Ks[rA * 64 + (((0 * 4 + g) ^ (rA & 7)) << 3)];
            s[kt] = __builtin_amdgcn_mfma_f32_16x16x32_bf16(a0, qf0, s[kt], 0, 0, 0);
            bf16x8 a1 = *(bf16x8*)&Ks[rA * 64 + (((1 * 4 + g) ^ (rA & 7)) << 3)];
            s[kt] = __builtin_amdgcn_mfma_f32_16x16x32_bf16(a1, qf1, s[kt], 0, 0, 0);
        }
        __builtin_amdgcn_s_setprio(0);

        float pv[4][4];
        float tmax = -1e30f;
#pragma unroll
        for (int kt = 0; kt < 4; ++kt) {
#pragma unroll
            for (int r = 0; r < 4; ++r) {
                float mv = Ms[(wq * 16 + cc) * 65 + kt * 16 + g * 4 + r];
                float svv = (mv == 0.f) ? -1e30f : s[kt][r];
                pv[kt][r] = svv;
                tmax = fmaxf(tmax, svv);
            }
        }
        tmax = fmaxf(tmax, __shfl_xor(tmax, 16));
        tmax = fmaxf(tmax, __shfl_xor(tmax, 32));
        float mnew = fmaxf(m_run, tmax);
        float rescale = __expf((m_run - mnew) * scale);
        float psum = 0.f;
#pragma unroll
        for (int kt = 0; kt < 4; ++kt) {
#pragma unroll
            for (int r = 0; r < 4; ++r) {
                float sv = pv[kt][r];
                float p = (sv == -1e30f) ? 0.f : __expf((sv - mnew) * scale);
                pv[kt][r] = p;
                psum += p;
            }
        }
        psum += __shfl_xor(psum, 16);
        psum += __shfl_xor(psum, 32);
        l_run = l_run * rescale + psum;
        m_run = mnew;
#pragma unroll
        for (int dt = 0; dt < 4; ++dt) {
            o[dt][0] *= rescale; o[dt][1] *= rescale;
            o[dt][2] *= rescale; o[dt][3] *= rescale;
        }

#pragma unroll
        for (int kt = 0; kt < 4; ++kt) {
            bf16x4 pk = {f2bf(pv[kt][0]), f2bf(pv[kt][1]),
                         f2bf(pv[kt][2]), f2bf(pv[kt][3])};
            *(bf16x4*)&Pl[wq][cc * 72 + kt * 16 + g * 4] = pk;
        }
        bf16x8 pf0 = *(bf16x8*)&Pl[wq][cc * 72 + 0 + g * 8];
        bf16x8 pf1 = *(bf16x8*)&Pl[wq][cc * 72 + 32 + g * 8];

        __builtin_amdgcn_s_setprio(1);
#pragma unroll
        for (int dt = 0; dt < 4; ++dt) {
            int rV = dt * 16 + cc;
            bf16x8 vf0 = *(bf16x8*)&Vt[rV * 64 + (((0 * 4 + g) ^ (rV & 7)) << 3)];
            o[dt] = __builtin_amdgcn_mfma_f32_16x16x32_bf16(vf0, pf0, o[dt], 0, 0, 0);
            bf16x8 vf1 = *(bf16x8*)&Vt[rV * 64 + (((1 * 4 + g) ^ (rV & 7)) << 3)];
            o[dt] = __builtin_amdgcn_mfma_f32_16x16x32_bf16(vf1, pf1, o[dt], 0, 0, 0);
        }
        __builtin_amdgcn_s_setprio(0);
        __syncthreads();
    }

    float invl = 1.f / l_run;
#pragma unroll
    for (int dt = 0; dt < 4; ++dt) {
        ushort4 w = {(unsigned short)f2bf(o[dt][0] * invl),
                     (unsigned short)f2bf(o[dt][1] * invl),
                     (unsigned short)f2bf(o[dt][2] * invl),
                     (unsigned short)f2bf(o[dt][3] * invl)};
        *(ushort4*)&AO[((size_t)(b * Nn + q0 + wq * 16 + cc)) * Hh +
                       h * HDd + dt * 16 + g * 4] = w;
    }
}

// ---------------------------------------------------------------------------
// GRU elementwise reading fused gate buffer G [M, 3072] (gx +0, gh +1536)
// ---------------------------------------------------------------------------
__global__ __launch_bounds__(256) void gru_kernel(
    const unsigned short* __restrict__ G,
    const float* __restrict__ msg, unsigned short* __restrict__ u)
{
    int i4 = blockIdx.x * 256 + threadIdx.x;
    int e = i4 * 4;
    int row = e >> 9, col = e & 511;
    const unsigned short* gxr = G + (size_t)row * GS;
    const unsigned short* ghr = gxr + 1536;
    ushort4 xr4 = *(const ushort4*)(gxr + col);
    ushort4 xz4 = *(const ushort4*)(gxr + col + 512);
    ushort4 xn4 = *(const ushort4*)(gxr + col + 1024);
    ushort4 hr4 = *(const ushort4*)(ghr + col);
    ushort4 hz4 = *(const ushort4*)(ghr + col + 512);
    ushort4 hn4 = *(const ushort4*)(ghr + col + 1024);
    float4 mg4 = *(const float4*)(msg + e);
    float mv[4] = {mg4.x, mg4.y, mg4.z, mg4.w};
    unsigned short xr[4] = {xr4.x, xr4.y, xr4.z, xr4.w};
    unsigned short xz[4] = {xz4.x, xz4.y, xz4.z, xz4.w};
    unsigned short xn[4] = {xn4.x, xn4.y, xn4.z, xn4.w};
    unsigned short hr[4] = {hr4.x, hr4.y, hr4.z, hr4.w};
    unsigned short hz[4] = {hz4.x, hz4.y, hz4.z, hz4.w};
    unsigned short hn[4] = {hn4.x, hn4.y, hn4.z, hn4.w};
    ushort4 out;
    unsigned short* op = (unsigned short*)&out;
#pragma unroll
    for (int j = 0; j < 4; ++j) {
        float r = 1.f / (1.f + __expf(-(b2f(xr[j]) + b2f(hr[j]))));
        float z = 1.f / (1.f + __expf(-(b2f(xz[j]) + b2f(hz[j]))));
        float n = tanhf(b2f(xn[j]) + r * b2f(hn[j]));
        op[j] = (unsigned short)f2bf((1.f - z) * n + z * mv[j]);
    }
    *(ushort4*)(u + e) = out;
}

// ---------------------------------------------------------------------------
// LayerNorm over rows of 512 (f32 in, f32 out)
// ---------------------------------------------------------------------------
__global__ __launch_bounds__(256) void ln_kernel(
    const float* __restrict__ Y, const float* __restrict__ g,
    const float* __restrict__ be, float* __restrict__ out)
{
    int row = blockIdx.x, t = threadIdx.x;
    const float* yr = Y + (size_t)row * Hh;
    float v0 = yr[t], v1 = yr[t + 256];
    float s = v0 + v1, s2 = v0 * v0 + v1 * v1;
#pragma unroll
    for (int o = 1; o < 64; o <<= 1) {
        s += __shfl_xor(s, o);
        s2 += __shfl_xor(s2, o);
    }
    __shared__ float rs[4], rs2[4];
    int w = t >> 6;
    if ((t & 63) == 0) { rs[w] = s; rs2[w] = s2; }
    __syncthreads();
    float ts = rs[0] + rs[1] + rs[2] + rs[3];
    float ts2 = rs2[0] + rs2[1] + rs2[2] + rs2[3];
    float mu = ts * (1.0f / Hh);
    float var = ts2 * (1.0f / Hh) - mu * mu;
    float rstd = rsqrtf(var + EPSs);
    out[(size_t)row * Hh + t] = (v0 - mu) * rstd * g[t] + be[t];
    out[(size_t)row * Hh + t + 256] = (v1 - mu) * rstd * g[t + 256] + be[t + 256];
}

// ---------------------------------------------------------------------------
extern "C" void kernel_launch(void* const* d_in, const int* in_sizes, int n_in,
                              void* d_out, int out_size, void* d_ws, size_t ws_size,
                              hipStream_t stream) {
    const float* messages = (const float*)d_in[0];
    const float* dist     = (const float*)d_in[1];
    const float* mask     = (const float*)d_in[2];
    const float* emb      = (const float*)d_in[3];
    const float* Wdq = (const float*)d_in[4];  const float* bdq = (const float*)d_in[5];
    const float* Wdk = (const float*)d_in[6];  const float* bdk = (const float*)d_in[7];
    const float* Wq  = (const float*)d_in[8];  const float* bq  = (const float*)d_in[9];
    const float* Wk  = (const float*)d_in[10]; const float* bk  = (const float*)d_in[11];
    const float* Wv  = (const float*)d_in[12]; const float* bv  = (const float*)d_in[13];
    const float* Wo  = (const float*)d_in[14]; const float* bo  = (const float*)d_in[15];
    const float* W_ih = (const float*)d_in[16]; const float* b_ih = (const float*)d_in[17];
    const float* W_hh = (const float*)d_in[18]; const float* b_hh = (const float*)d_in[19];
    const float* W1  = (const float*)d_in[20]; const float* b1  = (const float*)d_in[21];
    const float* W2  = (const float*)d_in[22]; const float* b2  = (const float*)d_in[23];
    const float* g2  = (const float*)d_in[24]; const float* beta2 = (const float*)d_in[25];

    const int M = Bz * Nn;  // 2048
    char* ws = (char*)d_ws;

    unsigned short* wdqb  = (unsigned short*)(ws + 0);         // [1024,64] wdq|wdk
    unsigned short* wdkb  = (unsigned short*)(ws + 65536);
    unsigned short* Wbigq = (unsigned short*)(ws + 131072);    // [512,768] Wq|FQ
    unsigned short* Wbigk = (unsigned short*)(ws + 917504);    // [512,768] Wk|FK
    unsigned short* wvb   = (unsigned short*)(ws + 1703936);   // [512,512]
    unsigned short* wihb  = (unsigned short*)(ws + 2228224);   // [1536,512]
    unsigned short* whhb  = (unsigned short*)(ws + 3801088);   // [1536,512]
    unsigned short* w1b   = (unsigned short*)(ws + 5373952);   // [2048,512]
    unsigned short* w2b   = (unsigned short*)(ws + 7471104);   // [512,2048]
    unsigned short* msgs  = (unsigned short*)(ws + 9568256);   // [2048,512]
    unsigned short* AQ    = (unsigned short*)(ws + 11665408);  // [2048,768] msgs|histq
    unsigned short* AK    = (unsigned short*)(ws + 14811136);  // [2048,768] msgs|histk
    unsigned short* embb  = (unsigned short*)(ws + 17956864);  // [256,64]
    unsigned short* EcatT = (unsigned short*)(ws + 17989632);  // [256,1024]
    unsigned short* woT   = (unsigned short*)(ws + 18513920);  // [512,512]
    unsigned short* Wfih  = (unsigned short*)(ws + 19038208);  // [1536,512]
    unsigned short* QKVb  = (unsigned short*)(ws + 20611072);  // [2048,1536]
    unsigned short* AO    = (unsigned short*)(ws + 26902528);  // [2048,512]
    unsigned short* G     = (unsigned short*)(ws + 28999680);  // [2048,3072]
    unsigned short* ub    = (unsigned short*)(ws + 41582592);  // [2048,512]
    unsigned short* f1    = (unsigned short*)(ws + 43679744);  // [2048,2048]
    float*          yb    = (float*)(ws + 52068352);           // [2048,512] f32
    float*          bqp   = (float*)(ws + 56262656);           // [512]
    float*          bkp   = (float*)(ws + 56264704);           // [512]
    float*          bgxp  = (float*)(ws + 56266752);           // [1536]

    dim3 blk(256);

    // 0) prep: conversions, hist, folds, Wo^T
    PrepArgs pa;
    pa.cs[0]  = {messages, msgs,  M * Hh,        512, 512};
    pa.cs[1]  = {messages, AQ,    M * Hh,        512, 768};
    pa.cs[2]  = {messages, AK,    M * Hh,        512, 768};
    pa.cs[3]  = {Wdq,      wdqb,  Hh * DEe,      64,  64};
    pa.cs[4]  = {Wdk,      wdkb,  Hh * DEe,      64,  64};
    pa.cs[5]  = {Wq,       Wbigq, Hh * Hh,       512, 768};
    pa.cs[6]  = {Wk,       Wbigk, Hh * Hh,       512, 768};
    pa.cs[7]  = {Wv,       wvb,   Hh * Hh,       512, 512};
    pa.cs[8]  = {W_ih,     wihb,  3 * Hh * Hh,   512, 512};
    pa.cs[9]  = {W_hh,     whhb,  3 * Hh * Hh,   512, 512};
    pa.cs[10] = {W1,       w1b,   DFFf * Hh,     512, 512};
    pa.cs[11] = {W2,       w2b,   Hh * DFFf,     2048, 2048};
    pa.emb = emb; pa.embb = embb;
    pa.dist = dist; pa.AQ = AQ; pa.AK = AK;
    pa.Wo = Wo; pa.woT = woT;
    pa.fW[0] = Wq;   pa.fv[0] = bdq; pa.fb[0] = bq;   pa.fo[0] = bqp;
    pa.fW[1] = Wk;   pa.fv[1] = bdk; pa.fb[1] = bk;   pa.fo[1] = bkp;
    pa.fW[2] = W_ih; pa.fv[2] = bo;  pa.fb[2] = b_ih; pa.fo[2] = bgxp;
    prep_kernel<<<2792, blk, 0, stream>>>(pa);

    // 1) EcatT = embb @ (Wdq|Wdk)^T   [256,1024]
    {
        SegArgs sa = {};
        sa.s[0] = {embb, wdqb, nullptr, nullptr, EcatT, 64, 64, 64, 0, 1024, 0};
        mgf_kernel<64, 128, 0, 0, 0, 0><<<dim3(8, 4), blk, 0, stream>>>(sa, 1024);
    }

    // 2) FQ|FK = (Wq|Wk) @ EcatT-slices  -> Wbig cols 512..768
    {
        SegArgs sa = {};
        sa.s[0] = {Wbigq, EcatT,       nullptr, nullptr, Wbigq + 512, 768, 512, 1024, 0, 768, 0};
        sa.s[1] = {Wbigk, EcatT + 512, nullptr, nullptr, Wbigk + 512, 768, 512, 1024, 0, 768, 0};
        mgf_kernel<64, 64, 0, 0, 0, 0><<<dim3(8, 8), blk, 0, stream>>>(sa, 256);
    }

    // 3) Wfih = W_ih @ Wo  (via woT)
    {
        SegArgs sa = {};
        sa.s[0] = {wihb, woT, nullptr, nullptr, Wfih, 512, 512, 512, 0, 512, 0};
        mgf_kernel<64, 128, 0, 0, 0, 0><<<dim3(4, 24), blk, 0, stream>>>(sa, 512);
    }

    // 4) mega GEMM: Q | K | V | gh0 | gh1 | gh2   (N=3072)
    {
        SegArgs sa = {};
        sa.s[0] = {AQ,   Wbigq,             bqp,          nullptr, QKVb,        768, 768, 768, 0, QS, 0};
        sa.s[1] = {AK,   Wbigk,             bkp,          nullptr, QKVb + 512,  768, 768, 768, 0, QS, 0};
        sa.s[2] = {msgs, wvb,               bv,           nullptr, QKVb + 1024, 512, 512, 512, 0, QS, 0};
        sa.s[3] = {msgs, whhb,              b_hh,         nullptr, G + 1536,    512, 512, 512, 0, GS, 0};
        sa.s[4] = {msgs, whhb + 512 * 512,  b_hh + 512,   nullptr, G + 2048,    512, 512, 512, 0, GS, 0};
        sa.s[5] = {msgs, whhb + 1024 * 512, b_hh + 1024,  nullptr, G + 2560,    512, 512, 512, 0, GS, 0};
        mgf_kernel<64, 128, 0, 0, 0, 1><<<dim3(24, 32), blk, 0, stream>>>(sa, 512);
    }

    // 5) attention
    attn_mfma_kernel<<<dim3(Nn / 64, NHh, Bz), blk, 0, stream>>>(QKVb, mask, AO);

    // 6) gx = AO @ Wfih^T + bgx'
    {
        SegArgs sa = {};
        sa.s[0] = {AO, Wfih, bgxp, nullptr, G, 512, 512, 512, 0, GS, 0};
        mgf_kernel<64, 128, 0, 0, 0, 1><<<dim3(12, 32), blk, 0, stream>>>(sa, 1536);
    }

    // 7) GRU elementwise
    gru_kernel<<<(M * Hh) / 1024, blk, 0, stream>>>(G, messages, ub);

    // 8) FFN
    {
        SegArgs sa = {};
        sa.s[0] = {ub, w1b, b1, nullptr, f1, 512, 512, 512, 0, DFFf, 0};
        mgf_kernel<64, 128, 1, 0, 0, 1><<<dim3(16, 32), blk, 0, stream>>>(sa, 2048);
    }
    {
        SegArgs sa = {};
        sa.s[0] = {f1, w2b, b2, ub, yb, 2048, 2048, 2048, 512, 512, 0};
        mgf_kernel<64, 64, 0, 2, 1, 1><<<dim3(8, 32), blk, 0, stream>>>(sa, 512);
    }

    // 9) LayerNorm -> out
    ln_kernel<<<M, blk, 0, stream>>>(yb, g2, beta2, (float*)d_out);
}

// Round 10
// 120.555 us; speedup vs baseline: 1.0360x; 1.0360x over previous
//
#include <hip/hip_runtime.h>
#include <hip/hip_bf16.h>
#include <math.h>

#define Bz 4
#define Nn 512
#define Hh 512
#define NHh 8
#define HDd 64
#define DEe 64
#define DFFf 2048
#define EPSs 1e-5f
#define QS 1536      // fused QKV row stride
#define GS 3072      // fused gate row stride

typedef __attribute__((ext_vector_type(8))) short bf16x8;
typedef __attribute__((ext_vector_type(4))) short bf16x4;
typedef __attribute__((ext_vector_type(4))) float f32x4;

__device__ inline short f2bf(float x) {
    unsigned u = __builtin_bit_cast(unsigned, x);
    unsigned r = (u + 0x7FFFu + ((u >> 16) & 1u)) >> 16;
    return (short)r;
}
__device__ inline float b2f(unsigned short u) {
    unsigned v = ((unsigned)u) << 16;
    return __builtin_bit_cast(float, v);
}
__device__ inline void gld16(const void* g, void* l) {
    __builtin_amdgcn_global_load_lds(
        (const __attribute__((address_space(1))) void*)g,
        (__attribute__((address_space(3))) void*)l, 16, 0, 0);
}

// ---------------------------------------------------------------------------
// prep: f32->bf16 copies | embb=emb/512 pad256 | bias folds | Wo transpose |
// histq (dist rows) | histk (dist cols) | mask bitpack.
// ---------------------------------------------------------------------------
struct CvtSeg { const float* src; unsigned short* dst; int n, ncols, pitch; };
struct PrepArgs {
    CvtSeg cs[10];
    const float* emb; unsigned short* embb;
    const float* dist;
    unsigned short* histq; unsigned short* histk;   // [2048,256]
    const float* Wo; unsigned short* woT;
    const float* mask; unsigned long long* mbits;   // [4*512*8]
    const float* fW[3]; const float* fv[3]; const float* fb[3]; float* fo[3];
};

__global__ __launch_bounds__(256) void prep_kernel(PrepArgs a)
{
    __shared__ char lds[17408];
    int t = threadIdx.x;
    int blk = blockIdx.x;
    if (blk < 512) {
        for (int sg = 0; sg < 10; ++sg) {
            CvtSeg c = a.cs[sg];
            int n4 = c.n >> 2;
            for (int i = blk * 256 + t; i < n4; i += 512 * 256) {
                int base = i * 4;
                int row = base / c.ncols;
                int col = base - row * c.ncols;
                float4 v = *(const float4*)(c.src + base);
                ushort4 o = {(unsigned short)f2bf(v.x), (unsigned short)f2bf(v.y),
                             (unsigned short)f2bf(v.z), (unsigned short)f2bf(v.w)};
                *(ushort4*)(c.dst + (size_t)row * c.pitch + col) = o;
            }
        }
        const float sc = 1.0f / 512.0f;
        for (int i = blk * 256 + t; i < 4096; i += 512 * 256) {
            ushort4 o = {0, 0, 0, 0};
            if (i * 4 < 201 * 64) {
                float4 v = *(const float4*)(a.emb + i * 4);
                o.x = (unsigned short)f2bf(v.x * sc);
                o.y = (unsigned short)f2bf(v.y * sc);
                o.z = (unsigned short)f2bf(v.z * sc);
                o.w = (unsigned short)f2bf(v.w * sc);
            }
            *(ushort4*)(a.embb + i * 4) = o;
        }
    } else if (blk < 552) {
        // bias folds: out = base + W @ vec   (all K=512)
        int fid = blk - 512;
        int f, ob;
        if (fid < 8)       { f = 0; ob = fid * 64; }
        else if (fid < 16) { f = 1; ob = (fid - 8) * 64; }
        else               { f = 2; ob = (fid - 16) * 64; }
        int i = ob + (t >> 2), part = t & 3;
        const float* Wr = a.fW[f] + (size_t)i * 512 + part * 128;
        const float* vv = a.fv[f] + part * 128;
        float s = 0.f;
        for (int k = 0; k < 128; k += 4) {
            float4 w4 = *(const float4*)(Wr + k);
            float4 b4 = *(const float4*)(vv + k);
            s += w4.x * b4.x + w4.y * b4.y + w4.z * b4.z + w4.w * b4.w;
        }
        s += __shfl_xor(s, 1);
        s += __shfl_xor(s, 2);
        if (part == 0) a.fo[f][i] = a.fb[f][i] + s;
    } else if (blk < 616) {
        // woT[m][i] = Wo[i][m], bf16 out
        int tid = blk - 552;
        int ti = tid >> 3, tj = tid & 7;
        float (*T)[68] = (float (*)[68])lds;
        int rr = t >> 4, c4 = (t & 15) * 4;
#pragma unroll
        for (int p = 0; p < 4; ++p) {
            int r = rr + p * 16;
            float4 v = *(const float4*)(a.Wo + (size_t)(ti * 64 + r) * 512 + tj * 64 + c4);
            *(float4*)&T[r][c4] = v;
        }
        __syncthreads();
#pragma unroll
        for (int p = 0; p < 4; ++p) {
            int jr = rr + p * 16;
            ushort4 o = {(unsigned short)f2bf(T[c4 + 0][jr]),
                         (unsigned short)f2bf(T[c4 + 1][jr]),
                         (unsigned short)f2bf(T[c4 + 2][jr]),
                         (unsigned short)f2bf(T[c4 + 3][jr])};
            *(ushort4*)(a.woT + (size_t)(tj * 64 + jr) * 512 + ti * 64 + c4) = o;
        }
    } else if (blk < 2664) {
        // histq: one block per dist row
        int r = blk - 616;
        int* hist = (int*)lds;
        hist[t] = 0;
        __syncthreads();
        float2 v = *(const float2*)(a.dist + (size_t)r * 512 + t * 2);
        atomicAdd(&hist[min(max((int)v.x, 0), 200)], 1);
        atomicAdd(&hist[min(max((int)v.y, 0), 200)], 1);
        __syncthreads();
        a.histq[(size_t)r * 256 + t] = (unsigned short)f2bf((float)hist[t]);
    } else if (blk < 2792) {
        // histk: per-column histograms, 16 cols per block
        int idx = blk - 2664;
        int b = idx >> 5, jt = idx & 31;
        int j0 = jt * 16;
        int* h2 = (int*)lds;           // [16][256]
        for (int k = t; k < 4096; k += 256) h2[k] = 0;
        __syncthreads();
        int ri = t >> 4, jj = t & 15;
        for (int i0 = 0; i0 < 512; i0 += 16) {
            float v = a.dist[(size_t)(b * 512 + i0 + ri) * 512 + j0 + jj];
            atomicAdd(&h2[jj * 256 + min(max((int)v, 0), 200)], 1);
        }
        __syncthreads();
        for (int k = t; k < 4096; k += 256) {
            int jj2 = k >> 8, bin = k & 255;
            a.histk[(size_t)(b * 512 + j0 + jj2) * 256 + bin] =
                (unsigned short)f2bf((float)h2[k]);
        }
    } else {
        // mask bitpack: mbits[row*8 + w] = ballot over 64 cols
        int idx = blk - 2792;          // 0..255
        int wv = t >> 6, lane = t & 63;
#pragma unroll
        for (int i = 0; i < 16; ++i) {
            int word = (idx * 4 + wv) * 16 + i;    // 0..16383
            int rowg = word >> 3, w = word & 7;
            float mv = a.mask[(size_t)rowg * 512 + w * 64 + lane];
            unsigned long long bits = __ballot(mv != 0.0f);
            if (lane == 0) a.mbits[word] = bits;
        }
    }
}

// ---------------------------------------------------------------------------
// Grouped bf16 MFMA GEMM with split-K A operand:
// k < ksplit reads A (lda); k >= ksplit reads A2 (lda2, offset k-ksplit).
// Per-segment M (early-exit). LDS double-buffered 2-phase.
// ---------------------------------------------------------------------------
struct Seg {
    const unsigned short* A; const unsigned short* A2;
    const unsigned short* W;
    const float* bias; const void* res; void* C;
    int lda, lda2, ksplit, Ks, ldw, rlda, ldc, Ms;
};
struct SegArgs { Seg s[6]; };

template<int BM, int BN, int RELU, int RESM, int OUTF, int HASB>
__global__ __launch_bounds__(256) void mgf_kernel(SegArgs sa, int SW)
{
    constexpr int WM = BM / 2, WN = BN / 2;
    constexpr int MT = WM / 16, NT = WN / 16;
    constexpr int IPA = BM / 32, IPB = BN / 32;
    __shared__ unsigned short As[2][BM * 64];
    __shared__ unsigned short Bs[2][BN * 64];
    int t = threadIdx.x, lane = t & 63, wid = t >> 6;
    int wm = wid >> 1, wn = wid & 1;
    int m0 = blockIdx.y * BM, n0 = blockIdx.x * BN;
    int seg = n0 / SW;
    if (m0 >= sa.s[seg].Ms) return;
    const unsigned short* A = sa.s[seg].A;
    const unsigned short* A2 = sa.s[seg].A2;
    const unsigned short* W = sa.s[seg].W;
    int lda = sa.s[seg].lda, lda2 = sa.s[seg].lda2, ksplit = sa.s[seg].ksplit;
    int Ks = sa.s[seg].Ks, ldw = sa.s[seg].ldw;
    int nloc = n0 - seg * SW;
    int lrow8 = lane >> 3;
    int lunit = (lane & 7) ^ lrow8;

    f32x4 acc[MT][NT] = {};

    auto stage = [&](int buf, int kt) {
        const unsigned short* Asrc;
        int koff, ldaa;
        if (kt < ksplit) { Asrc = A; koff = kt; ldaa = lda; }
        else             { Asrc = A2; koff = kt - ksplit; ldaa = lda2; }
#pragma unroll
        for (int i = 0; i < IPA; ++i) {
            int c = wid * IPA + i;
            gld16(Asrc + (size_t)(m0 + c * 8 + lrow8) * ldaa + koff + lunit * 8,
                  &As[buf][c * 512]);
        }
#pragma unroll
        for (int i = 0; i < IPB; ++i) {
            int c = wid * IPB + i;
            gld16(W + (size_t)(nloc + c * 8 + lrow8) * ldw + kt + lunit * 8,
                  &Bs[buf][c * 512]);
        }
    };

    stage(0, 0);
    __syncthreads();
    int cur = 0;
    for (int kt = 0; kt < Ks; kt += 64) {
        if (kt + 64 < Ks) stage(cur ^ 1, kt + 64);
#pragma unroll
        for (int kk = 0; kk < 2; ++kk) {
            bf16x8 fa[MT], fb[NT];
            int ub = kk * 4 + (lane >> 4);
#pragma unroll
            for (int mt = 0; mt < MT; ++mt) {
                int r = wm * WM + mt * 16 + (lane & 15);
                fa[mt] = *(const bf16x8*)&As[cur][r * 64 + ((ub ^ (r & 7)) << 3)];
            }
#pragma unroll
            for (int nt = 0; nt < NT; ++nt) {
                int r = wn * WN + nt * 16 + (lane & 15);
                fb[nt] = *(const bf16x8*)&Bs[cur][r * 64 + ((ub ^ (r & 7)) << 3)];
            }
#pragma unroll
            for (int mt = 0; mt < MT; ++mt)
#pragma unroll
                for (int nt = 0; nt < NT; ++nt)
                    acc[mt][nt] = __builtin_amdgcn_mfma_f32_16x16x32_bf16(
                        fa[mt], fb[nt], acc[mt][nt], 0, 0, 0);
        }
        __syncthreads();
        cur ^= 1;
    }

    int cr = (lane >> 4) * 4, ccl = lane & 15;
    const float* bias = sa.s[seg].bias;
    const void* res = sa.s[seg].res;
    int rlda = sa.s[seg].rlda, ldc = sa.s[seg].ldc;
    void* C = sa.s[seg].C;
#pragma unroll
    for (int mt = 0; mt < MT; ++mt) {
#pragma unroll
        for (int nt = 0; nt < NT; ++nt) {
            int lcol = nloc + wn * WN + nt * 16 + ccl;
            float bv = HASB ? bias[lcol] : 0.f;
#pragma unroll
            for (int r = 0; r < 4; ++r) {
                int row = m0 + wm * WM + mt * 16 + cr + r;
                float o = acc[mt][nt][r] + bv;
                if (RESM == 1)
                    o += ((const float*)res)[(size_t)row * rlda + lcol];
                if (RESM == 2)
                    o += b2f(((const unsigned short*)res)[(size_t)row * rlda + lcol]);
                if (RELU) o = fmaxf(o, 0.f);
                if (OUTF)
                    ((float*)C)[(size_t)row * ldc + lcol] = o;
                else
                    ((unsigned short*)C)[(size_t)row * ldc + lcol] =
                        (unsigned short)f2bf(o);
            }
        }
    }
}

// ---------------------------------------------------------------------------
// MFMA flash attention; mask via bitpacked u64 words (1 broadcast load/tile).
// ---------------------------------------------------------------------------
__global__ __launch_bounds__(256) void attn_mfma_kernel(
    const unsigned short* __restrict__ QKV,
    const unsigned long long* __restrict__ mbits,
    unsigned short* __restrict__ AO)
{
    __shared__ unsigned short Qs[64 * 64];
    __shared__ unsigned short Ks[64 * 64];
    __shared__ unsigned short Vt[64 * 64];
    __shared__ unsigned short Pl[4][16 * 72];

    int t = threadIdx.x;
    int lane = t & 63;
    int wq = t >> 6;
    int g = lane >> 4, cc = lane & 15;
    int q0 = blockIdx.x * 64;
    int h = blockIdx.y, b = blockIdx.z;

    int lr = t >> 2;
    int u0 = (t & 3) * 2;

    {
        const unsigned short* src =
            QKV + ((size_t)(b * Nn + q0 + lr)) * QS + h * HDd + u0 * 8;
        bf16x8 p0 = *(const bf16x8*)(src);
        bf16x8 p1 = *(const bf16x8*)(src + 8);
        *(bf16x8*)&Qs[lr * 64 + ((u0 ^ (lr & 7)) << 3)] = p0;
        *(bf16x8*)&Qs[lr * 64 + (((u0 + 1) ^ (lr & 7)) << 3)] = p1;
    }

    const unsigned short* Krow =
        QKV + ((size_t)(b * Nn + lr)) * QS + 512 + h * HDd + u0 * 8;
    int vkey = t >> 4;
    int vd0 = (t & 15) * 4;
    const unsigned short* Vbase =
        QKV + ((size_t)(b * Nn)) * QS + 1024 + h * HDd + vd0;
    const unsigned long long* Mb =
        mbits + ((size_t)(b * Nn + q0 + wq * 16 + cc)) * 8;

    bf16x8 kr0, kr1;
    ushort4 vr[4];
    auto issue = [&](int kc) {
        int k0 = kc * 64;
        const unsigned short* kp = Krow + (size_t)k0 * QS;
        kr0 = *(const bf16x8*)(kp);
        kr1 = *(const bf16x8*)(kp + 8);
#pragma unroll
        for (int p = 0; p < 4; ++p)
            vr[p] = *(const ushort4*)(Vbase + (size_t)(k0 + vkey + p * 16) * QS);
    };
    issue(0);
    __syncthreads();

    bf16x8 qf0 = *(bf16x8*)&Qs[(wq * 16 + cc) * 64 + (((0 * 4 + g) ^ (cc & 7)) << 3)];
    bf16x8 qf1 = *(bf16x8*)&Qs[(wq * 16 + cc) * 64 + (((1 * 4 + g) ^ (cc & 7)) << 3)];

    const float scale = 0.125f;
    float m_run = -1e30f, l_run = 0.f;
    f32x4 o[4] = {};

    for (int kc = 0; kc < 8; ++kc) {
        {
            *(bf16x8*)&Ks[lr * 64 + ((u0 ^ (lr & 7)) << 3)] = kr0;
            *(bf16x8*)&Ks[lr * 64 + (((u0 + 1) ^ (lr & 7)) << 3)] = kr1;
#pragma unroll
            for (int p = 0; p < 4; ++p) {
                int key = vkey + p * 16;
                unsigned short vals[4] = {vr[p].x, vr[p].y, vr[p].z, vr[p].w};
#pragma unroll
                for (int jj = 0; jj < 4; ++jj) {
                    int j = (jj + (t >> 2)) & 3;
                    int d = vd0 + j;
                    Vt[d * 64 + (key ^ ((d & 7) << 3))] = vals[j];
                }
            }
        }
        unsigned long long mw = Mb[kc];
        __syncthreads();
        if (kc < 7) issue(kc + 1);

        f32x4 s[4] = {};
        __builtin_amdgcn_s_setprio(1);
#pragma unroll
        for (int kt = 0; kt < 4; ++kt) {
            int rA = kt * 16 + cc;
            bf16x8 a0 = *(bf16x8*)&Ks[rA * 64 + (((0 * 4 + g) ^ (rA & 7)) << 3)];
            s[kt] = __builtin_amdgcn_mfma_f32_16x16x32_bf16(a0, qf0, s[kt], 0, 0, 0);
            bf16x8 a1 = *(bf16x8*)&Ks[rA * 64 + (((1 * 4 + g) ^ (rA & 7)) << 3)];
            s[kt] = __builtin_amdgcn_mfma_f32_16x16x32_bf16(a1, qf1, s[kt], 0, 0, 0);
        }
        __builtin_amdgcn_s_setprio(0);

        float pv[4][4];
        float tmax = -1e30f;
#pragma unroll
        for (int kt = 0; kt < 4; ++kt) {
#pragma unroll
            for (int r = 0; r < 4; ++r) {
                int kpos = kt * 16 + g * 4 + r;
                float svv = ((mw >> kpos) & 1ull) ? s[kt][r] : -1e30f;
                pv[kt][r] = svv;
                tmax = fmaxf(tmax, svv);
            }
        }
        tmax = fmaxf(tmax, __shfl_xor(tmax, 16));
        tmax = fmaxf(tmax, __shfl_xor(tmax, 32));
        float mnew = fmaxf(m_run, tmax);
        float rescale = __expf((m_run - mnew) * scale);
        float psum = 0.f;
#pragma unroll
        for (int kt = 0; kt < 4; ++kt) {
#pragma unroll
            for (int r = 0; r < 4; ++r) {
                float sv = pv[kt][r];
                float p = (sv == -1e30f) ? 0.f : __expf((sv - mnew) * scale);
                pv[kt][r] = p;
                psum += p;
            }
        }
        psum += __shfl_xor(psum, 16);
        psum += __shfl_xor(psum, 32);
        l_run = l_run * rescale + psum;
        m_run = mnew;
#pragma unroll
        for (int dt = 0; dt < 4; ++dt) {
            o[dt][0] *= rescale; o[dt][1] *= rescale;
            o[dt][2] *= rescale; o[dt][3] *= rescale;
        }

#pragma unroll
        for (int kt = 0; kt < 4; ++kt) {
            bf16x4 pk = {f2bf(pv[kt][0]), f2bf(pv[kt][1]),
                         f2bf(pv[kt][2]), f2bf(pv[kt][3])};
            *(bf16x4*)&Pl[wq][cc * 72 + kt * 16 + g * 4] = pk;
        }
        bf16x8 pf0 = *(bf16x8*)&Pl[wq][cc * 72 + 0 + g * 8];
        bf16x8 pf1 = *(bf16x8*)&Pl[wq][cc * 72 + 32 + g * 8];

        __builtin_amdgcn_s_setprio(1);
#pragma unroll
        for (int dt = 0; dt < 4; ++dt) {
            int rV = dt * 16 + cc;
            bf16x8 vf0 = *(bf16x8*)&Vt[rV * 64 + (((0 * 4 + g) ^ (rV & 7)) << 3)];
            o[dt] = __builtin_amdgcn_mfma_f32_16x16x32_bf16(vf0, pf0, o[dt], 0, 0, 0);
            bf16x8 vf1 = *(bf16x8*)&Vt[rV * 64 + (((1 * 4 + g) ^ (rV & 7)) << 3)];
            o[dt] = __builtin_amdgcn_mfma_f32_16x16x32_bf16(vf1, pf1, o[dt], 0, 0, 0);
        }
        __builtin_amdgcn_s_setprio(0);
        __syncthreads();
    }

    float invl = 1.f / l_run;
#pragma unroll
    for (int dt = 0; dt < 4; ++dt) {
        ushort4 w = {(unsigned short)f2bf(o[dt][0] * invl),
                     (unsigned short)f2bf(o[dt][1] * invl),
                     (unsigned short)f2bf(o[dt][2] * invl),
                     (unsigned short)f2bf(o[dt][3] * invl)};
        *(ushort4*)&AO[((size_t)(b * Nn + q0 + wq * 16 + cc)) * Hh +
                       h * HDd + dt * 16 + g * 4] = w;
    }
}

// ---------------------------------------------------------------------------
// GRU elementwise reading fused gate buffer G [M, 3072] (gx +0, gh +1536)
// ---------------------------------------------------------------------------
__global__ __launch_bounds__(256) void gru_kernel(
    const unsigned short* __restrict__ G,
    const float* __restrict__ msg, unsigned short* __restrict__ u)
{
    int i4 = blockIdx.x * 256 + threadIdx.x;
    int e = i4 * 4;
    int row = e >> 9, col = e & 511;
    const unsigned short* gxr = G + (size_t)row * GS;
    const unsigned short* ghr = gxr + 1536;
    ushort4 xr4 = *(const ushort4*)(gxr + col);
    ushort4 xz4 = *(const ushort4*)(gxr + col + 512);
    ushort4 xn4 = *(const ushort4*)(gxr + col + 1024);
    ushort4 hr4 = *(const ushort4*)(ghr + col);
    ushort4 hz4 = *(const ushort4*)(ghr + col + 512);
    ushort4 hn4 = *(const ushort4*)(ghr + col + 1024);
    float4 mg4 = *(const float4*)(msg + e);
    float mv[4] = {mg4.x, mg4.y, mg4.z, mg4.w};
    unsigned short xr[4] = {xr4.x, xr4.y, xr4.z, xr4.w};
    unsigned short xz[4] = {xz4.x, xz4.y, xz4.z, xz4.w};
    unsigned short xn[4] = {xn4.x, xn4.y, xn4.z, xn4.w};
    unsigned short hr[4] = {hr4.x, hr4.y, hr4.z, hr4.w};
    unsigned short hz[4] = {hz4.x, hz4.y, hz4.z, hz4.w};
    unsigned short hn[4] = {hn4.x, hn4.y, hn4.z, hn4.w};
    ushort4 out;
    unsigned short* op = (unsigned short*)&out;
#pragma unroll
    for (int j = 0; j < 4; ++j) {
        float r = 1.f / (1.f + __expf(-(b2f(xr[j]) + b2f(hr[j]))));
        float z = 1.f / (1.f + __expf(-(b2f(xz[j]) + b2f(hz[j]))));
        float n = tanhf(b2f(xn[j]) + r * b2f(hn[j]));
        op[j] = (unsigned short)f2bf((1.f - z) * n + z * mv[j]);
    }
    *(ushort4*)(u + e) = out;
}

// ---------------------------------------------------------------------------
// LayerNorm over rows of 512 (f32 in, f32 out)
// ---------------------------------------------------------------------------
__global__ __launch_bounds__(256) void ln_kernel(
    const float* __restrict__ Y, const float* __restrict__ g,
    const float* __restrict__ be, float* __restrict__ out)
{
    int row = blockIdx.x, t = threadIdx.x;
    const float* yr = Y + (size_t)row * Hh;
    float v0 = yr[t], v1 = yr[t + 256];
    float s = v0 + v1, s2 = v0 * v0 + v1 * v1;
#pragma unroll
    for (int o = 1; o < 64; o <<= 1) {
        s += __shfl_xor(s, o);
        s2 += __shfl_xor(s2, o);
    }
    __shared__ float rs[4], rs2[4];
    int w = t >> 6;
    if ((t & 63) == 0) { rs[w] = s; rs2[w] = s2; }
    __syncthreads();
    float ts = rs[0] + rs[1] + rs[2] + rs[3];
    float ts2 = rs2[0] + rs2[1] + rs2[2] + rs2[3];
    float mu = ts * (1.0f / Hh);
    float var = ts2 * (1.0f / Hh) - mu * mu;
    float rstd = rsqrtf(var + EPSs);
    out[(size_t)row * Hh + t] = (v0 - mu) * rstd * g[t] + be[t];
    out[(size_t)row * Hh + t + 256] = (v1 - mu) * rstd * g[t + 256] + be[t + 256];
}

// ---------------------------------------------------------------------------
extern "C" void kernel_launch(void* const* d_in, const int* in_sizes, int n_in,
                              void* d_out, int out_size, void* d_ws, size_t ws_size,
                              hipStream_t stream) {
    const float* messages = (const float*)d_in[0];
    const float* dist     = (const float*)d_in[1];
    const float* mask     = (const float*)d_in[2];
    const float* emb      = (const float*)d_in[3];
    const float* Wdq = (const float*)d_in[4];  const float* bdq = (const float*)d_in[5];
    const float* Wdk = (const float*)d_in[6];  const float* bdk = (const float*)d_in[7];
    const float* Wq  = (const float*)d_in[8];  const float* bq  = (const float*)d_in[9];
    const float* Wk  = (const float*)d_in[10]; const float* bk  = (const float*)d_in[11];
    const float* Wv  = (const float*)d_in[12]; const float* bv  = (const float*)d_in[13];
    const float* Wo  = (const float*)d_in[14]; const float* bo  = (const float*)d_in[15];
    const float* W_ih = (const float*)d_in[16]; const float* b_ih = (const float*)d_in[17];
    const float* W_hh = (const float*)d_in[18]; const float* b_hh = (const float*)d_in[19];
    const float* W1  = (const float*)d_in[20]; const float* b1  = (const float*)d_in[21];
    const float* W2  = (const float*)d_in[22]; const float* b2  = (const float*)d_in[23];
    const float* g2  = (const float*)d_in[24]; const float* beta2 = (const float*)d_in[25];

    const int M = Bz * Nn;  // 2048
    char* ws = (char*)d_ws;

    unsigned short* wdqb  = (unsigned short*)(ws + 0);         // [512,64]
    unsigned short* wdkb  = (unsigned short*)(ws + 65536);     // [512,64]
    unsigned short* Wbigq = (unsigned short*)(ws + 131072);    // [512,768] Wq|FQ
    unsigned short* Wbigk = (unsigned short*)(ws + 917504);    // [512,768] Wk|FK
    unsigned short* wvb   = (unsigned short*)(ws + 1703936);   // [512,512]
    unsigned short* wihb  = (unsigned short*)(ws + 2228224);   // [1536,512]
    unsigned short* whhb  = (unsigned short*)(ws + 3801088);   // [1536,512]
    unsigned short* w1b   = (unsigned short*)(ws + 5373952);   // [2048,512]
    unsigned short* w2b   = (unsigned short*)(ws + 7471104);   // [512,2048]
    unsigned short* msgs  = (unsigned short*)(ws + 9568256);   // [2048,512]
    unsigned short* histq = (unsigned short*)(ws + 11665408);  // [2048,256]
    unsigned short* histk = (unsigned short*)(ws + 12713984);  // [2048,256]
    unsigned short* embb  = (unsigned short*)(ws + 13762560);  // [256,64]
    unsigned short* EcatTq= (unsigned short*)(ws + 13795328);  // [256,512]
    unsigned short* EcatTk= (unsigned short*)(ws + 14057472);  // [256,512]
    unsigned short* woT   = (unsigned short*)(ws + 14319616);  // [512,512]
    unsigned short* Wfih  = (unsigned short*)(ws + 14843904);  // [1536,512]
    unsigned short* QKVb  = (unsigned short*)(ws + 16416768);  // [2048,1536]
    unsigned short* AO    = (unsigned short*)(ws + 22708224);  // [2048,512]
    unsigned short* G     = (unsigned short*)(ws + 24805376);  // [2048,3072]
    unsigned short* ub    = (unsigned short*)(ws + 37388288);  // [2048,512]
    unsigned short* f1    = (unsigned short*)(ws + 39485440);  // [2048,2048]
    float*          yb    = (float*)(ws + 47874048);           // [2048,512] f32
    float*          bqp   = (float*)(ws + 52068352);           // [512]
    float*          bkp   = (float*)(ws + 52070400);           // [512]
    float*          bgxp  = (float*)(ws + 52072448);           // [1536]
    unsigned long long* mbits = (unsigned long long*)(ws + 52078592); // [16384]

    dim3 blk(256);

    // 0) prep
    PrepArgs pa;
    pa.cs[0] = {messages, msgs,  M * Hh,      512,  512};
    pa.cs[1] = {Wdq,      wdqb,  Hh * DEe,    64,   64};
    pa.cs[2] = {Wdk,      wdkb,  Hh * DEe,    64,   64};
    pa.cs[3] = {Wq,       Wbigq, Hh * Hh,     512,  768};
    pa.cs[4] = {Wk,       Wbigk, Hh * Hh,     512,  768};
    pa.cs[5] = {Wv,       wvb,   Hh * Hh,     512,  512};
    pa.cs[6] = {W_ih,     wihb,  3 * Hh * Hh, 512,  512};
    pa.cs[7] = {W_hh,     whhb,  3 * Hh * Hh, 512,  512};
    pa.cs[8] = {W1,       w1b,   DFFf * Hh,   512,  512};
    pa.cs[9] = {W2,       w2b,   Hh * DFFf,   2048, 2048};
    pa.emb = emb; pa.embb = embb;
    pa.dist = dist; pa.histq = histq; pa.histk = histk;
    pa.Wo = Wo; pa.woT = woT;
    pa.mask = mask; pa.mbits = mbits;
    pa.fW[0] = Wq;   pa.fv[0] = bdq; pa.fb[0] = bq;   pa.fo[0] = bqp;
    pa.fW[1] = Wk;   pa.fv[1] = bdk; pa.fb[1] = bk;   pa.fo[1] = bkp;
    pa.fW[2] = W_ih; pa.fv[2] = bo;  pa.fb[2] = b_ih; pa.fo[2] = bgxp;
    prep_kernel<<<3048, blk, 0, stream>>>(pa);

    // 1) grouped: EcatTq = embb@Wdq^T | EcatTk = embb@Wdk^T | Wfih = W_ih@Wo
    {
        SegArgs sa = {};
        sa.s[0] = {embb, nullptr, wdqb, nullptr, nullptr, EcatTq,
                   64, 0, 9999, 64, 64, 0, 512, 256};
        sa.s[1] = {embb, nullptr, wdkb, nullptr, nullptr, EcatTk,
                   64, 0, 9999, 64, 64, 0, 512, 256};
        sa.s[2] = {wihb, nullptr, woT, nullptr, nullptr, Wfih,
                   512, 0, 9999, 512, 512, 0, 512, 1536};
        mgf_kernel<64, 64, 0, 0, 0, 0><<<dim3(24, 24), blk, 0, stream>>>(sa, 512);
    }

    // 2) grouped: FQ = Wq@EcatTq^T | FK = Wk@EcatTk^T  -> Wbig cols 512..768
    {
        SegArgs sa = {};
        sa.s[0] = {Wbigq, nullptr, EcatTq, nullptr, nullptr, Wbigq + 512,
                   768, 0, 9999, 512, 512, 0, 768, 512};
        sa.s[1] = {Wbigk, nullptr, EcatTk, nullptr, nullptr, Wbigk + 512,
                   768, 0, 9999, 512, 512, 0, 768, 512};
        mgf_kernel<64, 64, 0, 0, 0, 0><<<dim3(8, 8), blk, 0, stream>>>(sa, 256);
    }

    // 3) mega GEMM: Q | K | V | gh0 | gh1 | gh2   (N=3072)
    {
        SegArgs sa = {};
        sa.s[0] = {msgs, histq, Wbigq,             bqp,         nullptr, QKVb,
                   512, 256, 512, 768, 768, 0, QS, 2048};
        sa.s[1] = {msgs, histk, Wbigk,             bkp,         nullptr, QKVb + 512,
                   512, 256, 512, 768, 768, 0, QS, 2048};
        sa.s[2] = {msgs, nullptr, wvb,             bv,          nullptr, QKVb + 1024,
                   512, 0, 9999, 512, 512, 0, QS, 2048};
        sa.s[3] = {msgs, nullptr, whhb,            b_hh,        nullptr, G + 1536,
                   512, 0, 9999, 512, 512, 0, GS, 2048};
        sa.s[4] = {msgs, nullptr, whhb + 512 * 512, b_hh + 512, nullptr, G + 2048,
                   512, 0, 9999, 512, 512, 0, GS, 2048};
        sa.s[5] = {msgs, nullptr, whhb + 1024 * 512, b_hh + 1024, nullptr, G + 2560,
                   512, 0, 9999, 512, 512, 0, GS, 2048};
        mgf_kernel<64, 128, 0, 0, 0, 1><<<dim3(24, 32), blk, 0, stream>>>(sa, 512);
    }

    // 4) attention
    attn_mfma_kernel<<<dim3(Nn / 64, NHh, Bz), blk, 0, stream>>>(QKVb, mbits, AO);

    // 5) gx = AO @ Wfih^T + bgx'
    {
        SegArgs sa = {};
        sa.s[0] = {AO, nullptr, Wfih, bgxp, nullptr, G,
                   512, 0, 9999, 512, 512, 0, GS, 2048};
        mgf_kernel<64, 128, 0, 0, 0, 1><<<dim3(12, 32), blk, 0, stream>>>(sa, 1536);
    }

    // 6) GRU elementwise
    gru_kernel<<<(M * Hh) / 1024, blk, 0, stream>>>(G, messages, ub);

    // 7) FFN
    {
        SegArgs sa = {};
        sa.s[0] = {ub, nullptr, w1b, b1, nullptr, f1,
                   512, 0, 9999, 512, 512, 0, DFFf, 2048};
        mgf_kernel<64, 128, 1, 0, 0, 1><<<dim3(16, 32), blk, 0, stream>>>(sa, 2048);
    }
    {
        SegArgs sa = {};
        sa.s[0] = {f1, nullptr, w2b, b2, ub, yb,
                   2048, 0, 9999, 2048, 2048, 512, 512, 2048};
        mgf_kernel<64, 64, 0, 2, 1, 1><<<dim3(8, 32), blk, 0, stream>>>(sa, 512);
    }

    // 8) LayerNorm -> out
    ln_kernel<<<M, blk, 0, stream>>>(yb, g2, beta2, (float*)d_out);
}